// Round 2
// baseline (12567.363 us; speedup 1.0000x reference)
//
#include <hip/hip_runtime.h>
#include <hip/hip_bf16.h>
#include <stdint.h>

typedef __attribute__((ext_vector_type(8))) short bf16x8;
typedef __attribute__((ext_vector_type(4))) float f32x4;

#define S_LEN 512
#define B_DIM 64
#define E_DIM 512
#define H_DIM 768
#define G4    3072      // 4H (one direction's gate width)
#define H2    1536      // 2H (combined hs row)
#define M_ROWS 32768    // S*B
#define CHUNK 128       // seq steps per X-chunk
#define CM    8192      // CHUNK*B rows per chunk
#define NWG   48

__device__ __forceinline__ float sigmf_(float x) { return 1.0f / (1.0f + __expf(-x)); }
__device__ __forceinline__ float tanhf2(float x) {
  x = fminf(fmaxf(x, -20.0f), 20.0f);
  float e = __expf(2.0f * x);
  return (e - 1.0f) / (e + 1.0f);
}

// ---------------- embedding gather + cast to bf16 ----------------
__global__ __launch_bounds__(256) void k_gather(const int* __restrict__ tokens,
                                                const float* __restrict__ emb,
                                                __hip_bfloat16* __restrict__ out) {
  const int t = blockIdx.x * 256 + threadIdx.x;   // 2,097,152 threads, 8 elems each
  const int e0 = t * 8;
  const int row = e0 >> 9;        // /512
  const int k = e0 & 511;
  const int tok = tokens[row];
  const float4* p = (const float4*)(emb + (size_t)tok * E_DIM + k);
  const float4 v0 = p[0], v1 = p[1];
  __align__(16) __hip_bfloat16 tmp[8];
  tmp[0] = __float2bfloat16(v0.x); tmp[1] = __float2bfloat16(v0.y);
  tmp[2] = __float2bfloat16(v0.z); tmp[3] = __float2bfloat16(v0.w);
  tmp[4] = __float2bfloat16(v1.x); tmp[5] = __float2bfloat16(v1.y);
  tmp[6] = __float2bfloat16(v1.z); tmp[7] = __float2bfloat16(v1.w);
  *(bf16x8*)(out + (size_t)t * 8) = *(const bf16x8*)tmp;
}

// ---------------- fp32 -> bf16 transpose (LDS tiled): dst[c*Rs+r]=src[r*Cs+c] ----------------
__global__ __launch_bounds__(256) void k_transpose_cast(const float* __restrict__ src,
                                                        __hip_bfloat16* __restrict__ dst,
                                                        int Rs, int Cs) {
  __shared__ float tile[32][33];
  const int tx = threadIdx.x & 31, ty = threadIdx.x >> 5;
  const int c0 = blockIdx.x * 32, r0 = blockIdx.y * 32;
  #pragma unroll
  for (int i = ty; i < 32; i += 8)
    tile[i][tx] = src[(size_t)(r0 + i) * Cs + c0 + tx];
  __syncthreads();
  #pragma unroll
  for (int i = ty; i < 32; i += 8)
    dst[(size_t)(c0 + i) * Rs + r0 + tx] = __float2bfloat16(tile[tx][i]);
}

// ---------------- combined bias for one direction: bi + bh ----------------
__global__ __launch_bounds__(256) void k_bias(const float* __restrict__ bi,
                                              const float* __restrict__ bh,
                                              float* __restrict__ bias) {
  const int n = blockIdx.x * 256 + threadIdx.x;   // 3072
  bias[n] = bi[n] + bh[n];
}

// ---------------- chunk GEMM: Xc[8192,3072] = EmbChunk[8192,512] @ WiT^T + bias ----------------
__global__ __launch_bounds__(256) void k_gemm_x(const __hip_bfloat16* __restrict__ A,  // [8192,512]
                                                const __hip_bfloat16* __restrict__ BT, // [3072,512]
                                                const float* __restrict__ bias,        // [3072]
                                                __hip_bfloat16* __restrict__ C) {      // [8192,3072]
  __shared__ __align__(16) __hip_bfloat16 As[128][40];
  __shared__ __align__(16) __hip_bfloat16 Bs[128][40];
  const int tid = threadIdx.x;
  const int wave = tid >> 6, lane = tid & 63;
  const int q = lane >> 4, lr = lane & 15;
  const int wm = (wave >> 1) * 64, wn = (wave & 1) * 64;
  const int m0 = blockIdx.y * 128, n0 = blockIdx.x * 128;
  const int srow = tid >> 2, skseg = (tid & 3) * 8;

  f32x4 acc[4][4];
  #pragma unroll
  for (int i = 0; i < 4; ++i)
    #pragma unroll
    for (int j = 0; j < 4; ++j) { f32x4 z = {0.f, 0.f, 0.f, 0.f}; acc[i][j] = z; }

  for (int kt = 0; kt < 16; ++kt) {
    __syncthreads();
    const int kbase = kt * 32 + skseg;
    *(bf16x8*)&As[srow][skseg]      = *(const bf16x8*)(A + (size_t)(m0 + srow) * E_DIM + kbase);
    *(bf16x8*)&As[srow + 64][skseg] = *(const bf16x8*)(A + (size_t)(m0 + srow + 64) * E_DIM + kbase);
    *(bf16x8*)&Bs[srow][skseg]      = *(const bf16x8*)(BT + (size_t)(n0 + srow) * E_DIM + kbase);
    *(bf16x8*)&Bs[srow + 64][skseg] = *(const bf16x8*)(BT + (size_t)(n0 + srow + 64) * E_DIM + kbase);
    __syncthreads();
    bf16x8 af[4], bfr[4];
    #pragma unroll
    for (int mt = 0; mt < 4; ++mt) af[mt] = *(const bf16x8*)&As[wm + mt * 16 + lr][q * 8];
    #pragma unroll
    for (int nt = 0; nt < 4; ++nt) bfr[nt] = *(const bf16x8*)&Bs[wn + nt * 16 + lr][q * 8];
    #pragma unroll
    for (int mt = 0; mt < 4; ++mt)
      #pragma unroll
      for (int nt = 0; nt < 4; ++nt)
        acc[mt][nt] = __builtin_amdgcn_mfma_f32_16x16x32_bf16(af[mt], bfr[nt], acc[mt][nt], 0, 0, 0);
  }
  #pragma unroll
  for (int mt = 0; mt < 4; ++mt) {
    #pragma unroll
    for (int nt = 0; nt < 4; ++nt) {
      const int col = n0 + wn + nt * 16 + lr;
      const float bv = bias[col];
      #pragma unroll
      for (int i = 0; i < 4; ++i) {
        const int row = m0 + wm + mt * 16 + q * 4 + i;
        C[(size_t)row * G4 + col] = __float2bfloat16(acc[mt][nt][i] + bv);
      }
    }
  }
}

// ---------------- forward LSTM scan (one chunk of 128 steps), persistent 48 WGs ----------------
__global__ __launch_bounds__(256) void k_fwd_scan(const __hip_bfloat16* __restrict__ X,    // [8192,3072] chunk
                                                  const __hip_bfloat16* __restrict__ WhTf, // [3072,768]
                                                  __hip_bfloat16* __restrict__ hbuf,       // [2][64][768]
                                                  __hip_bfloat16* __restrict__ Hs,         // [32768,1536]
                                                  float* __restrict__ cstate,              // [64,768]
                                                  float* __restrict__ hT,                  // [64,768]
                                                  int* __restrict__ bar,                   // cnt, gen
                                                  int chunk) {
  const int wg = blockIdx.x;           // owns h cols [16wg, 16wg+16)
  const int tid = threadIdx.x;
  const int wave = tid >> 6;           // = gate index (r,f,g,o)
  const int lane = tid & 63;
  const int q = lane >> 4, lr = lane & 15;
  const int base = chunk * CHUNK;

  __shared__ float g_lds[4][64][17];
  __shared__ float c_lds[64][17];
  for (int i = tid; i < 64 * 16; i += 256) {
    const int row = i >> 4, col = i & 15;
    c_lds[row][col] = cstate[row * H_DIM + wg * 16 + col];
  }

  // persistent B fragments: this wave's 16 WhT^f rows (gate cols), 24 k-tiles in VGPRs
  const __hip_bfloat16* Bptr = WhTf + (size_t)(wave * H_DIM + wg * 16 + lr) * H_DIM + q * 8;
  bf16x8 breg[24];
  #pragma unroll
  for (int kt = 0; kt < 24; ++kt) breg[kt] = *(const bf16x8*)(Bptr + kt * 32);
  __syncthreads();

  for (int s = 0; s < CHUNK; ++s) {
    const __hip_bfloat16* hcur = hbuf + (size_t)(s & 1) * (B_DIM * H_DIM);
    __hip_bfloat16* hnxt = hbuf + (size_t)((s + 1) & 1) * (B_DIM * H_DIM);

    f32x4 acc[4];
    #pragma unroll
    for (int mt = 0; mt < 4; ++mt) { f32x4 z = {0.f, 0.f, 0.f, 0.f}; acc[mt] = z; }
    #pragma unroll
    for (int kt = 0; kt < 24; ++kt) {
      const int k = kt * 32 + q * 8;
      #pragma unroll
      for (int mt = 0; mt < 4; ++mt) {
        bf16x8 a = *(const bf16x8*)(hcur + (size_t)(mt * 16 + lr) * H_DIM + k);
        acc[mt] = __builtin_amdgcn_mfma_f32_16x16x32_bf16(a, breg[kt], acc[mt], 0, 0, 0);
      }
    }
    #pragma unroll
    for (int mt = 0; mt < 4; ++mt)
      #pragma unroll
      for (int i = 0; i < 4; ++i)
        g_lds[wave][mt * 16 + q * 4 + i][lr] = acc[mt][i];
    __syncthreads();

    {
      const int col = tid & 15;
      const int rg = tid >> 4;
      #pragma unroll
      for (int ii = 0; ii < 4; ++ii) {
        const int row = rg * 4 + ii;                 // batch index
        const size_t xoff = ((size_t)s * B_DIM + row) * G4 + wg * 16 + col;
        const float r = g_lds[0][row][col] + __bfloat162float(X[xoff]);
        const float f = g_lds[1][row][col] + __bfloat162float(X[xoff + 768]);
        const float g = g_lds[2][row][col] + __bfloat162float(X[xoff + 1536]);
        const float o = g_lds[3][row][col] + __bfloat162float(X[xoff + 2304]);
        const float c = sigmf_(f) * c_lds[row][col] + sigmf_(r) * tanhf2(g);
        const float h = sigmf_(o) * tanhf2(c);
        c_lds[row][col] = c;
        const __hip_bfloat16 hb = __float2bfloat16(h);
        const int hidx = row * H_DIM + wg * 16 + col;
        hnxt[hidx] = hb;
        Hs[((size_t)(base + s) * B_DIM + row) * H2 + wg * 16 + col] = hb;
        if (chunk == 3 && s == CHUNK - 1) hT[hidx] = h;
      }
    }

    // ---- device-scope grid barrier (h is double-buffered -> one barrier/step) ----
    __threadfence();            // release this WG's h stores
    __syncthreads();
    if (tid == 0) {
      const int gstep = base + s + 1;               // global completed steps
      const int target = NWG * gstep;
      const int old = __hip_atomic_fetch_add(&bar[0], 1, __ATOMIC_ACQ_REL, __HIP_MEMORY_SCOPE_AGENT);
      if (old == target - 1) {
        __hip_atomic_store(&bar[1], gstep, __ATOMIC_RELEASE, __HIP_MEMORY_SCOPE_AGENT);
      } else {
        long guard = 0;
        while (__hip_atomic_load(&bar[1], __ATOMIC_ACQUIRE, __HIP_MEMORY_SCOPE_AGENT) < gstep) {
          __builtin_amdgcn_s_sleep(2);
          if (++guard > (1L << 18)) break;   // fail visibly (wrong answer), never hang
        }
      }
    }
    __syncthreads();
    __threadfence();            // acquire: invalidate stale cached h
  }

  // persist c for next chunk
  for (int i = tid; i < 64 * 16; i += 256) {
    const int row = i >> 4, col = i & 15;
    cstate[row * H_DIM + wg * 16 + col] = c_lds[row][col];
  }
}

// ---------------- hTW[b,n] = hT[b,:] @ Wh_b[:,n]  (biases already in X) ----------------
__global__ __launch_bounds__(256) void k_hTW(const float* __restrict__ hT,   // [64,768]
                                             const float* __restrict__ Whb,  // [768,3072]
                                             float* __restrict__ hTW) {      // [64,3072]
  const int b = blockIdx.y;
  const int n = blockIdx.x * 256 + threadIdx.x;
  __shared__ float hs[768];
  for (int i = threadIdx.x; i < 768; i += 256) hs[i] = hT[b * 768 + i];
  __syncthreads();
  float acc = 0.f;
  #pragma unroll 4
  for (int k = 0; k < 768; ++k) acc += hs[k] * Whb[(size_t)k * G4 + n];
  hTW[(size_t)b * G4 + n] = acc;
}

// ---------------- backward scan (one chunk, reverse): 64*768 independent chains ----------------
__global__ __launch_bounds__(256) void k_bwd_scan(const __hip_bfloat16* __restrict__ X,   // [8192,3072] chunk
                                                  const float* __restrict__ hTW,          // [64,3072]
                                                  __hip_bfloat16* __restrict__ Hs,        // [32768,1536]
                                                  float* __restrict__ c2state,            // [49152]
                                                  int chunk) {
  const int t = blockIdx.x * 256 + threadIdx.x;    // 49152
  const int b = t / H_DIM;
  const int j = t % H_DIM;
  const int base = chunk * CHUNK;
  const float hw0 = hTW[(size_t)b * G4 + j];
  const float hw1 = hTW[(size_t)b * G4 + 768 + j];
  const float hw2 = hTW[(size_t)b * G4 + 1536 + j];
  const float hw3 = hTW[(size_t)b * G4 + 2304 + j];
  float c2 = c2state[t];
  for (int s = CHUNK - 1; s >= 0; --s) {
    const size_t xb = ((size_t)s * B_DIM + b) * G4 + j;
    const float r = sigmf_(__bfloat162float(X[xb]) + hw0);
    const float f = sigmf_(__bfloat162float(X[xb + 768]) + hw1);
    const float g = tanhf2(__bfloat162float(X[xb + 1536]) + hw2);
    const float o = sigmf_(__bfloat162float(X[xb + 2304]) + hw3);
    c2 = f * c2 + r * g;
    Hs[((size_t)(base + s) * B_DIM + b) * H2 + H_DIM + j] = __float2bfloat16(o * tanhf2(c2));
  }
  c2state[t] = c2;
}

// ---------------- output: out[i,l] = Hs[i,:] @ Wout + bout (+pad bias) ----------------
__global__ __launch_bounds__(256) void k_out(const __hip_bfloat16* __restrict__ Hs,
                                             const float* __restrict__ Wout,  // [1536,32]
                                             const float* __restrict__ bout,  // [32]
                                             const int* __restrict__ tokens,  // [32768]
                                             float* __restrict__ out) {       // [32768,32]
  __shared__ float rowbuf[8][1536];
  const int r0 = blockIdx.x * 8;
  const int tid = threadIdx.x;
  for (int idx = tid; idx < 8 * 1536; idx += 256) {
    const int rr = idx / 1536, k = idx % 1536;
    rowbuf[rr][k] = __bfloat162float(Hs[(size_t)(r0 + rr) * H2 + k]);
  }
  __syncthreads();
  const int l = tid & 31, rr = tid >> 5;
  float acc = bout[l];
  #pragma unroll 8
  for (int k = 0; k < 1536; ++k) acc += rowbuf[rr][k] * Wout[k * 32 + l];
  const int row = r0 + rr;
  if (l == 0 && tokens[row] == 1) acc += 10000.0f;
  out[(size_t)row * 32 + l] = acc;
}

// ---------------- host launcher ----------------
extern "C" void kernel_launch(void* const* d_in, const int* in_sizes, int n_in,
                              void* d_out, int out_size, void* d_ws, size_t ws_size,
                              hipStream_t stream) {
  const int*   tokens = (const int*)d_in[0];
  const float* emb    = (const float*)d_in[2];
  const float* Wi_f   = (const float*)d_in[3];
  const float* bi_f   = (const float*)d_in[4];
  const float* Wh_f   = (const float*)d_in[5];
  const float* bh_f   = (const float*)d_in[6];
  const float* Wi_b   = (const float*)d_in[7];
  const float* bi_b   = (const float*)d_in[8];
  const float* Wh_b   = (const float*)d_in[9];
  const float* bh_b   = (const float*)d_in[10];
  const float* Wout   = (const float*)d_in[11];
  const float* bout   = (const float*)d_in[12];
  float* out = (float*)d_out;
  char* ws = (char*)d_ws;

  size_t off = 0;
  auto alloc = [&](size_t bytes) { size_t o = off; off += (bytes + 255) & ~(size_t)255; return o; };
  const size_t oHs   = alloc((size_t)M_ROWS * H2 * 2);        // 100.7 MB  [hs_f|hs_b] bf16
  const size_t oX    = alloc((size_t)CM * G4 * 2);            // 50.3 MB   one chunk of gates
  const size_t oEmb  = alloc((size_t)M_ROWS * E_DIM * 2);     // 33.6 MB
  const size_t oWiT  = alloc((size_t)G4 * E_DIM * 2);         // 3.1 MB    (reused per direction)
  const size_t oWhTf = alloc((size_t)G4 * H_DIM * 2);         // 4.7 MB
  const size_t oBias = alloc((size_t)G4 * 4);
  const size_t oHbuf = alloc((size_t)2 * B_DIM * H_DIM * 2);
  const size_t oCst  = alloc((size_t)B_DIM * H_DIM * 4);
  const size_t oHT   = alloc((size_t)B_DIM * H_DIM * 4);
  const size_t oHTW  = alloc((size_t)B_DIM * G4 * 4);
  const size_t oC2   = alloc((size_t)B_DIM * H_DIM * 4);
  const size_t oBar  = alloc(256);
  (void)ws_size; (void)in_sizes; (void)n_in; (void)out_size;   // total ~194 MB

  __hip_bfloat16* Hs   = (__hip_bfloat16*)(ws + oHs);
  __hip_bfloat16* X    = (__hip_bfloat16*)(ws + oX);
  __hip_bfloat16* Emb  = (__hip_bfloat16*)(ws + oEmb);
  __hip_bfloat16* WiT  = (__hip_bfloat16*)(ws + oWiT);
  __hip_bfloat16* WhTf = (__hip_bfloat16*)(ws + oWhTf);
  float*          Bias = (float*)(ws + oBias);
  __hip_bfloat16* Hbuf = (__hip_bfloat16*)(ws + oHbuf);
  float*          Cst  = (float*)(ws + oCst);
  float*          HT   = (float*)(ws + oHT);
  float*          HTW  = (float*)(ws + oHTW);
  float*          C2   = (float*)(ws + oC2);
  int*            Bar  = (int*)(ws + oBar);

  hipMemsetAsync(ws + oHbuf, 0, (size_t)2 * B_DIM * H_DIM * 2, stream);
  hipMemsetAsync(ws + oCst, 0, (size_t)B_DIM * H_DIM * 4, stream);
  hipMemsetAsync(ws + oC2, 0, (size_t)B_DIM * H_DIM * 4, stream);
  hipMemsetAsync(ws + oBar, 0, 256, stream);

  k_gather<<<8192, 256, 0, stream>>>(tokens, emb, Emb);
  k_transpose_cast<<<dim3(96, 24), 256, 0, stream>>>(Wh_f, WhTf, 768, 3072);

  // ---- forward direction: 4 chunks of (GEMM -> scan) ----
  k_transpose_cast<<<dim3(96, 16), 256, 0, stream>>>(Wi_f, WiT, 512, 3072);
  k_bias<<<12, 256, 0, stream>>>(bi_f, bh_f, Bias);
  for (int c = 0; c < 4; ++c) {
    k_gemm_x<<<dim3(24, 64), 256, 0, stream>>>(Emb + (size_t)c * CM * E_DIM, WiT, Bias, X);
    k_fwd_scan<<<NWG, 256, 0, stream>>>(X, WhTf, Hbuf, Hs, Cst, HT, Bar, c);
  }

  // ---- backward direction: hT@Wh_b once, then 4 chunks in reverse ----
  k_hTW<<<dim3(12, 64), 256, 0, stream>>>(HT, Wh_b, HTW);
  k_transpose_cast<<<dim3(96, 16), 256, 0, stream>>>(Wi_b, WiT, 512, 3072);
  k_bias<<<12, 256, 0, stream>>>(bi_b, bh_b, Bias);
  for (int c = 3; c >= 0; --c) {
    k_gemm_x<<<dim3(24, 64), 256, 0, stream>>>(Emb + (size_t)c * CM * E_DIM, WiT, Bias, X);
    k_bwd_scan<<<192, 256, 0, stream>>>(X, HTW, Hs, C2, c);
  }

  k_out<<<4096, 256, 0, stream>>>(Hs, Wout, bout, tokens, out);
}

// Round 4
// 6025.061 us; speedup vs baseline: 2.0858x; 2.0858x over previous
//
#include <hip/hip_runtime.h>
#include <hip/hip_bf16.h>
#include <stdint.h>

typedef __attribute__((ext_vector_type(8))) short bf16x8;
typedef __attribute__((ext_vector_type(4))) float f32x4;

#define S_LEN 512
#define B_DIM 64
#define E_DIM 512
#define H_DIM 768
#define G4    3072      // 4H (one direction's gate width)
#define H2    1536      // 2H (combined hs row)
#define M_ROWS 32768    // S*B
#define CHUNK 128       // seq steps per X-chunk
#define CM    8192      // CHUNK*B rows per chunk
#define NSLICE 24       // h-col slices per batch group (32 cols each)

__device__ __forceinline__ float sigmf_(float x) { return 1.0f / (1.0f + __expf(-x)); }
__device__ __forceinline__ float tanhf2(float x) {
  x = fminf(fmaxf(x, -20.0f), 20.0f);
  float e = __expf(2.0f * x);
  return (e - 1.0f) / (e + 1.0f);
}

// ---------------- embedding gather + cast to bf16 ----------------
__global__ __launch_bounds__(256) void k_gather(const int* __restrict__ tokens,
                                                const float* __restrict__ emb,
                                                __hip_bfloat16* __restrict__ out) {
  const int t = blockIdx.x * 256 + threadIdx.x;
  const int e0 = t * 8;
  const int row = e0 >> 9;
  const int k = e0 & 511;
  const int tok = tokens[row];
  const float4* p = (const float4*)(emb + (size_t)tok * E_DIM + k);
  const float4 v0 = p[0], v1 = p[1];
  __align__(16) __hip_bfloat16 tmp[8];
  tmp[0] = __float2bfloat16(v0.x); tmp[1] = __float2bfloat16(v0.y);
  tmp[2] = __float2bfloat16(v0.z); tmp[3] = __float2bfloat16(v0.w);
  tmp[4] = __float2bfloat16(v1.x); tmp[5] = __float2bfloat16(v1.y);
  tmp[6] = __float2bfloat16(v1.z); tmp[7] = __float2bfloat16(v1.w);
  *(bf16x8*)(out + (size_t)t * 8) = *(const bf16x8*)tmp;
}

// ---------------- fp32 -> bf16 transpose (LDS tiled): dst[c*Rs+r]=src[r*Cs+c] ----------------
__global__ __launch_bounds__(256) void k_transpose_cast(const float* __restrict__ src,
                                                        __hip_bfloat16* __restrict__ dst,
                                                        int Rs, int Cs) {
  __shared__ float tile[32][33];
  const int tx = threadIdx.x & 31, ty = threadIdx.x >> 5;
  const int c0 = blockIdx.x * 32, r0 = blockIdx.y * 32;
  #pragma unroll
  for (int i = ty; i < 32; i += 8)
    tile[i][tx] = src[(size_t)(r0 + i) * Cs + c0 + tx];
  __syncthreads();
  #pragma unroll
  for (int i = ty; i < 32; i += 8)
    dst[(size_t)(c0 + i) * Rs + r0 + tx] = __float2bfloat16(tile[tx][i]);
}

// ---------------- combined bias for one direction: bi + bh ----------------
__global__ __launch_bounds__(256) void k_bias(const float* __restrict__ bi,
                                              const float* __restrict__ bh,
                                              float* __restrict__ bias) {
  const int n = blockIdx.x * 256 + threadIdx.x;
  bias[n] = bi[n] + bh[n];
}

// ---------------- chunk GEMM: Xc[8192,3072] = EmbChunk[8192,512] @ WiT^T + bias ----------------
__global__ __launch_bounds__(256) void k_gemm_x(const __hip_bfloat16* __restrict__ A,
                                                const __hip_bfloat16* __restrict__ BT,
                                                const float* __restrict__ bias,
                                                __hip_bfloat16* __restrict__ C) {
  __shared__ __align__(16) __hip_bfloat16 As[128][40];
  __shared__ __align__(16) __hip_bfloat16 Bs[128][40];
  const int tid = threadIdx.x;
  const int wave = tid >> 6, lane = tid & 63;
  const int q = lane >> 4, lr = lane & 15;
  const int wm = (wave >> 1) * 64, wn = (wave & 1) * 64;
  const int m0 = blockIdx.y * 128, n0 = blockIdx.x * 128;
  const int srow = tid >> 2, skseg = (tid & 3) * 8;

  f32x4 acc[4][4];
  #pragma unroll
  for (int i = 0; i < 4; ++i)
    #pragma unroll
    for (int j = 0; j < 4; ++j) { f32x4 z = {0.f, 0.f, 0.f, 0.f}; acc[i][j] = z; }

  for (int kt = 0; kt < 16; ++kt) {
    __syncthreads();
    const int kbase = kt * 32 + skseg;
    *(bf16x8*)&As[srow][skseg]      = *(const bf16x8*)(A + (size_t)(m0 + srow) * E_DIM + kbase);
    *(bf16x8*)&As[srow + 64][skseg] = *(const bf16x8*)(A + (size_t)(m0 + srow + 64) * E_DIM + kbase);
    *(bf16x8*)&Bs[srow][skseg]      = *(const bf16x8*)(BT + (size_t)(n0 + srow) * E_DIM + kbase);
    *(bf16x8*)&Bs[srow + 64][skseg] = *(const bf16x8*)(BT + (size_t)(n0 + srow + 64) * E_DIM + kbase);
    __syncthreads();
    bf16x8 af[4], bfr[4];
    #pragma unroll
    for (int mt = 0; mt < 4; ++mt) af[mt] = *(const bf16x8*)&As[wm + mt * 16 + lr][q * 8];
    #pragma unroll
    for (int nt = 0; nt < 4; ++nt) bfr[nt] = *(const bf16x8*)&Bs[wn + nt * 16 + lr][q * 8];
    #pragma unroll
    for (int mt = 0; mt < 4; ++mt)
      #pragma unroll
      for (int nt = 0; nt < 4; ++nt)
        acc[mt][nt] = __builtin_amdgcn_mfma_f32_16x16x32_bf16(af[mt], bfr[nt], acc[mt][nt], 0, 0, 0);
  }
  #pragma unroll
  for (int mt = 0; mt < 4; ++mt) {
    #pragma unroll
    for (int nt = 0; nt < 4; ++nt) {
      const int col = n0 + wn + nt * 16 + lr;
      const float bv = bias[col];
      #pragma unroll
      for (int i = 0; i < 4; ++i) {
        const int row = m0 + wm + mt * 16 + q * 4 + i;
        C[(size_t)row * G4 + col] = __float2bfloat16(acc[mt][nt][i] + bv);
      }
    }
  }
}

// ---------------- forward LSTM scan (one chunk of 128 steps) ----------------
// 96 persistent WGs = 4 batch groups (16 rows) x 24 col-slices (32 h-cols).
// h exchanged via relaxed agent-scope atomics (sc1: L2-bypassing, NO cache-invalidating
// fences -> weights/X stay L2-hot). Per-group 24-WG barrier. Wh in 192 VGPRs/lane.
__global__ __launch_bounds__(256, 1) void k_fwd_scan(const __hip_bfloat16* __restrict__ X,    // [8192,3072] chunk
                                                     const __hip_bfloat16* __restrict__ WhTf, // [3072,768]
                                                     __hip_bfloat16* __restrict__ hbuf,       // [2][64][768]
                                                     __hip_bfloat16* __restrict__ Hs,         // [32768,1536]
                                                     float* __restrict__ cstate,              // [64,768]
                                                     float* __restrict__ hT,                  // [64,768]
                                                     int* __restrict__ bar,                   // 4 groups x {cnt,gen}, stride 32 ints
                                                     int chunk) {
  const int bx = blockIdx.x;
  const int group = bx / NSLICE;       // batch rows [16g, 16g+16)
  const int slice = bx % NSLICE;       // h cols [32*slice, 32*slice+32)
  const int r0 = group * 16;
  const int j0 = slice * 32;
  const int tid = threadIdx.x;
  const int w = tid >> 6;              // wave = gate index (r,f,g,o)
  const int lane = tid & 63;
  const int q = lane >> 4, lr = lane & 15;
  const int base = chunk * CHUNK;

  __shared__ __align__(16) __hip_bfloat16 h_stage[16][776];  // +8 pad
  __shared__ float g_lds[4][16][33];
  __shared__ float c_lds[16][33];

  const int brow = tid >> 4;           // 0..15 (batch row within group)
  const int cp = (tid & 15) * 2;       // 0..30 (col pair within slice)

  // load persistent c slice
  {
    const float* cs = cstate + (size_t)(r0 + brow) * H_DIM + j0 + cp;
    c_lds[brow][cp] = cs[0];
    c_lds[brow][cp + 1] = cs[1];
  }

  // persistent weights: wave w = gate w, cols [j0, j0+32) -> 2 N-tiles, 24 K-tiles
  bf16x8 breg0[24], breg1[24];
  {
    const __hip_bfloat16* Bp = WhTf + ((size_t)(w * H_DIM + j0 + lr)) * H_DIM + q * 8;
    #pragma unroll
    for (int kt = 0; kt < 24; ++kt) {
      breg0[kt] = *(const bf16x8*)(Bp + kt * 32);
      breg1[kt] = *(const bf16x8*)(Bp + (size_t)16 * H_DIM + kt * 32);
    }
  }

  int* grpbar = bar + group * 32;

  for (int s = 0; s < CHUNK; ++s) {
    const int gs = base + s;
    const __hip_bfloat16* hcur = hbuf + (size_t)(gs & 1) * (B_DIM * H_DIM);
    __hip_bfloat16* hnxt = hbuf + (size_t)((gs + 1) & 1) * (B_DIM * H_DIM);

    // ---- stage this group's 16 h rows into LDS (coherent 8B loads) ----
    // row = 768 bf16 = 1536 B = 192 qwords; 16 lanes/row -> 12 iters  [R3 BUG: was 6]
    {
      const int srow = tid >> 4, sc = tid & 15;
      const unsigned long long* src = (const unsigned long long*)(hcur + (size_t)(r0 + srow) * H_DIM);
      unsigned long long* dst = (unsigned long long*)&h_stage[srow][0];
      #pragma unroll
      for (int it = 0; it < 12; ++it) {
        const int c8 = it * 16 + sc;
        dst[c8] = __hip_atomic_load(src + c8, __ATOMIC_RELAXED, __HIP_MEMORY_SCOPE_AGENT);
      }
    }
    __syncthreads();

    // ---- hidden GEMM for gate w: [16,768] x [768,32] ----
    f32x4 acc0 = {0.f, 0.f, 0.f, 0.f}, acc1 = {0.f, 0.f, 0.f, 0.f};
    #pragma unroll
    for (int kt = 0; kt < 24; ++kt) {
      bf16x8 a = *(const bf16x8*)&h_stage[lr][kt * 32 + q * 8];
      acc0 = __builtin_amdgcn_mfma_f32_16x16x32_bf16(a, breg0[kt], acc0, 0, 0, 0);
      acc1 = __builtin_amdgcn_mfma_f32_16x16x32_bf16(a, breg1[kt], acc1, 0, 0, 0);
    }
    #pragma unroll
    for (int i = 0; i < 4; ++i) {
      g_lds[w][q * 4 + i][lr] = acc0[i];
      g_lds[w][q * 4 + i][16 + lr] = acc1[i];
    }
    __syncthreads();

    // ---- nonlinearity + c/h update: each thread owns 2 cells ----
    {
      const size_t xr = ((size_t)s * B_DIM + r0 + brow) * G4 + j0;
      const float rv0 = g_lds[0][brow][cp]     + __bfloat162float(X[xr + cp]);
      const float rv1 = g_lds[0][brow][cp + 1] + __bfloat162float(X[xr + cp + 1]);
      const float fv0 = g_lds[1][brow][cp]     + __bfloat162float(X[xr + 768 + cp]);
      const float fv1 = g_lds[1][brow][cp + 1] + __bfloat162float(X[xr + 768 + cp + 1]);
      const float gv0 = g_lds[2][brow][cp]     + __bfloat162float(X[xr + 1536 + cp]);
      const float gv1 = g_lds[2][brow][cp + 1] + __bfloat162float(X[xr + 1536 + cp + 1]);
      const float ov0 = g_lds[3][brow][cp]     + __bfloat162float(X[xr + 2304 + cp]);
      const float ov1 = g_lds[3][brow][cp + 1] + __bfloat162float(X[xr + 2304 + cp + 1]);
      const float c0 = sigmf_(fv0) * c_lds[brow][cp]     + sigmf_(rv0) * tanhf2(gv0);
      const float c1 = sigmf_(fv1) * c_lds[brow][cp + 1] + sigmf_(rv1) * tanhf2(gv1);
      c_lds[brow][cp] = c0;
      c_lds[brow][cp + 1] = c1;
      const float h0 = sigmf_(ov0) * tanhf2(c0);
      const float h1 = sigmf_(ov1) * tanhf2(c1);
      __hip_bfloat162 hh;
      hh.x = __float2bfloat16(h0);
      hh.y = __float2bfloat16(h1);
      unsigned int hv;
      __builtin_memcpy(&hv, &hh, 4);
      __hip_atomic_store((unsigned int*)(hnxt + (size_t)(r0 + brow) * H_DIM + j0 + cp), hv,
                         __ATOMIC_RELAXED, __HIP_MEMORY_SCOPE_AGENT);
      *(unsigned int*)(Hs + ((size_t)gs * B_DIM + r0 + brow) * H2 + j0 + cp) = hv;
      if (chunk == 3 && s == CHUNK - 1) {
        hT[(size_t)(r0 + brow) * H_DIM + j0 + cp] = h0;
        hT[(size_t)(r0 + brow) * H_DIM + j0 + cp + 1] = h1;
      }
    }

    // ---- per-group barrier (syncthreads drains vmcnt -> all h stores at IC) ----
    __syncthreads();
    if (tid == 0) {
      const int gstep = gs + 1;
      const int old = __hip_atomic_fetch_add(&grpbar[0], 1, __ATOMIC_RELEASE, __HIP_MEMORY_SCOPE_AGENT);
      if (old == NSLICE * gstep - 1) {
        __hip_atomic_store(&grpbar[1], gstep, __ATOMIC_RELEASE, __HIP_MEMORY_SCOPE_AGENT);
      } else {
        long guard = 0;
        while (__hip_atomic_load(&grpbar[1], __ATOMIC_RELAXED, __HIP_MEMORY_SCOPE_AGENT) < gstep) {
          __builtin_amdgcn_s_sleep(1);
          if (++guard > (1L << 21)) break;   // fail visibly, never hang
        }
      }
    }
    __syncthreads();
  }

  // persist c for next chunk
  {
    float* cs = cstate + (size_t)(r0 + brow) * H_DIM + j0 + cp;
    cs[0] = c_lds[brow][cp];
    cs[1] = c_lds[brow][cp + 1];
  }
}

// ---------------- hTW[b,n] = hT[b,:] @ Wh_b[:,n] ----------------
__global__ __launch_bounds__(256) void k_hTW(const float* __restrict__ hT,
                                             const float* __restrict__ Whb,
                                             float* __restrict__ hTW) {
  const int b = blockIdx.y;
  const int n = blockIdx.x * 256 + threadIdx.x;
  __shared__ float hs[768];
  for (int i = threadIdx.x; i < 768; i += 256) hs[i] = hT[b * 768 + i];
  __syncthreads();
  float acc = 0.f;
  #pragma unroll 4
  for (int k = 0; k < 768; ++k) acc += hs[k] * Whb[(size_t)k * G4 + n];
  hTW[(size_t)b * G4 + n] = acc;
}

// ---------------- backward scan (one chunk, reverse): independent chains ----------------
__global__ __launch_bounds__(256) void k_bwd_scan(const __hip_bfloat16* __restrict__ X,
                                                  const float* __restrict__ hTW,
                                                  __hip_bfloat16* __restrict__ Hs,
                                                  float* __restrict__ c2state,
                                                  int chunk) {
  const int t = blockIdx.x * 256 + threadIdx.x;    // 49152
  const int b = t / H_DIM;
  const int j = t % H_DIM;
  const int base = chunk * CHUNK;
  const float hw0 = hTW[(size_t)b * G4 + j];
  const float hw1 = hTW[(size_t)b * G4 + 768 + j];
  const float hw2 = hTW[(size_t)b * G4 + 1536 + j];
  const float hw3 = hTW[(size_t)b * G4 + 2304 + j];
  float c2 = c2state[t];
  for (int s = CHUNK - 1; s >= 0; --s) {
    const size_t xb = ((size_t)s * B_DIM + b) * G4 + j;
    const float r = sigmf_(__bfloat162float(X[xb]) + hw0);
    const float f = sigmf_(__bfloat162float(X[xb + 768]) + hw1);
    const float g = tanhf2(__bfloat162float(X[xb + 1536]) + hw2);
    const float o = sigmf_(__bfloat162float(X[xb + 2304]) + hw3);
    c2 = f * c2 + r * g;
    Hs[((size_t)(base + s) * B_DIM + b) * H2 + H_DIM + j] = __float2bfloat16(o * tanhf2(c2));
  }
  c2state[t] = c2;
}

// ---------------- output: out[i,l] = Hs[i,:] @ Wout + bout (+pad bias) ----------------
__global__ __launch_bounds__(256) void k_out(const __hip_bfloat16* __restrict__ Hs,
                                             const float* __restrict__ Wout,
                                             const float* __restrict__ bout,
                                             const int* __restrict__ tokens,
                                             float* __restrict__ out) {
  __shared__ float rowbuf[8][1536];
  const int r0 = blockIdx.x * 8;
  const int tid = threadIdx.x;
  for (int idx = tid; idx < 8 * 1536; idx += 256) {
    const int rr = idx / 1536, k = idx % 1536;
    rowbuf[rr][k] = __bfloat162float(Hs[(size_t)(r0 + rr) * H2 + k]);
  }
  __syncthreads();
  const int l = tid & 31, rr = tid >> 5;
  float acc = bout[l];
  #pragma unroll 8
  for (int k = 0; k < 1536; ++k) acc += rowbuf[rr][k] * Wout[k * 32 + l];
  const int row = r0 + rr;
  if (l == 0 && tokens[row] == 1) acc += 10000.0f;
  out[(size_t)row * 32 + l] = acc;
}

// ---------------- host launcher ----------------
extern "C" void kernel_launch(void* const* d_in, const int* in_sizes, int n_in,
                              void* d_out, int out_size, void* d_ws, size_t ws_size,
                              hipStream_t stream) {
  const int*   tokens = (const int*)d_in[0];
  const float* emb    = (const float*)d_in[2];
  const float* Wi_f   = (const float*)d_in[3];
  const float* bi_f   = (const float*)d_in[4];
  const float* Wh_f   = (const float*)d_in[5];
  const float* bh_f   = (const float*)d_in[6];
  const float* Wi_b   = (const float*)d_in[7];
  const float* bi_b   = (const float*)d_in[8];
  const float* Wh_b   = (const float*)d_in[9];
  const float* bh_b   = (const float*)d_in[10];
  const float* Wout   = (const float*)d_in[11];
  const float* bout   = (const float*)d_in[12];
  float* out = (float*)d_out;
  char* ws = (char*)d_ws;

  size_t off = 0;
  auto alloc = [&](size_t bytes) { size_t o = off; off += (bytes + 255) & ~(size_t)255; return o; };
  const size_t oHs   = alloc((size_t)M_ROWS * H2 * 2);        // 100.7 MB
  const size_t oX    = alloc((size_t)CM * G4 * 2);            // 50.3 MB
  const size_t oEmb  = alloc((size_t)M_ROWS * E_DIM * 2);     // 33.6 MB
  const size_t oWiT  = alloc((size_t)G4 * E_DIM * 2);         // 3.1 MB
  const size_t oWhTf = alloc((size_t)G4 * H_DIM * 2);         // 4.7 MB
  const size_t oBias = alloc((size_t)G4 * 4);
  const size_t oHbuf = alloc((size_t)2 * B_DIM * H_DIM * 2);
  const size_t oCst  = alloc((size_t)B_DIM * H_DIM * 4);
  const size_t oHT   = alloc((size_t)B_DIM * H_DIM * 4);
  const size_t oHTW  = alloc((size_t)B_DIM * G4 * 4);
  const size_t oC2   = alloc((size_t)B_DIM * H_DIM * 4);
  const size_t oBar  = alloc(512);
  (void)ws_size; (void)in_sizes; (void)n_in; (void)out_size;   // total ~194 MB

  __hip_bfloat16* Hs   = (__hip_bfloat16*)(ws + oHs);
  __hip_bfloat16* X    = (__hip_bfloat16*)(ws + oX);
  __hip_bfloat16* Emb  = (__hip_bfloat16*)(ws + oEmb);
  __hip_bfloat16* WiT  = (__hip_bfloat16*)(ws + oWiT);
  __hip_bfloat16* WhTf = (__hip_bfloat16*)(ws + oWhTf);
  float*          Bias = (float*)(ws + oBias);
  __hip_bfloat16* Hbuf = (__hip_bfloat16*)(ws + oHbuf);
  float*          Cst  = (float*)(ws + oCst);
  float*          HT   = (float*)(ws + oHT);
  float*          HTW  = (float*)(ws + oHTW);
  float*          C2   = (float*)(ws + oC2);
  int*            Bar  = (int*)(ws + oBar);

  hipMemsetAsync(ws + oHbuf, 0, (size_t)2 * B_DIM * H_DIM * 2, stream);
  hipMemsetAsync(ws + oCst, 0, (size_t)B_DIM * H_DIM * 4, stream);
  hipMemsetAsync(ws + oC2, 0, (size_t)B_DIM * H_DIM * 4, stream);
  hipMemsetAsync(ws + oBar, 0, 512, stream);

  k_gather<<<8192, 256, 0, stream>>>(tokens, emb, Emb);
  k_transpose_cast<<<dim3(96, 24), 256, 0, stream>>>(Wh_f, WhTf, 768, 3072);

  // ---- forward direction: 4 chunks of (GEMM -> scan) ----
  k_transpose_cast<<<dim3(96, 16), 256, 0, stream>>>(Wi_f, WiT, 512, 3072);
  k_bias<<<12, 256, 0, stream>>>(bi_f, bh_f, Bias);
  for (int c = 0; c < 4; ++c) {
    k_gemm_x<<<dim3(24, 64), 256, 0, stream>>>(Emb + (size_t)c * CM * E_DIM, WiT, Bias, X);
    k_fwd_scan<<<96, 256, 0, stream>>>(X, WhTf, Hbuf, Hs, Cst, HT, Bar, c);
  }

  // ---- backward direction: hT@Wh_b once, then 4 chunks in reverse ----
  k_hTW<<<dim3(12, 64), 256, 0, stream>>>(HT, Wh_b, HTW);
  k_transpose_cast<<<dim3(96, 16), 256, 0, stream>>>(Wi_b, WiT, 512, 3072);
  k_bias<<<12, 256, 0, stream>>>(bi_b, bh_b, Bias);
  for (int c = 3; c >= 0; --c) {
    k_gemm_x<<<dim3(24, 64), 256, 0, stream>>>(Emb + (size_t)c * CM * E_DIM, WiT, Bias, X);
    k_bwd_scan<<<192, 256, 0, stream>>>(X, HTW, Hs, C2, c);
  }

  k_out<<<4096, 256, 0, stream>>>(Hs, Wout, bout, tokens, out);
}

// Round 5
// 5743.283 us; speedup vs baseline: 2.1882x; 1.0491x over previous
//
#include <hip/hip_runtime.h>
#include <hip/hip_bf16.h>
#include <stdint.h>

typedef __attribute__((ext_vector_type(8))) short bf16x8;
typedef __attribute__((ext_vector_type(4))) float f32x4;
typedef unsigned long long ull_t;

#define S_LEN 512
#define B_DIM 64
#define E_DIM 512
#define H_DIM 768
#define G4    3072      // 4H (one direction's gate width)
#define H2    1536      // 2H (combined hs row)
#define M_ROWS 32768    // S*B
#define CHUNK 128       // seq steps per X-chunk
#define CM    8192      // CHUNK*B rows per chunk
#define NSLICE 12       // h-col slices per batch group (64 cols each)

__device__ __forceinline__ float sigmf_(float x) { return 1.0f / (1.0f + __expf(-x)); }
__device__ __forceinline__ float tanhf2(float x) {
  x = fminf(fmaxf(x, -20.0f), 20.0f);
  float e = __expf(2.0f * x);
  return (e - 1.0f) / (e + 1.0f);
}
__device__ __forceinline__ float bf_lo(unsigned int u) { return __uint_as_float(u << 16); }
__device__ __forceinline__ float bf_hi(unsigned int u) { return __uint_as_float(u & 0xffff0000u); }
__device__ __forceinline__ unsigned int packbf2(float a, float b) {
  __hip_bfloat162 hh;
  hh.x = __float2bfloat16(a);
  hh.y = __float2bfloat16(b);
  unsigned int v;
  __builtin_memcpy(&v, &hh, 4);
  return v;
}

// ---------------- embedding gather + cast to bf16 ----------------
__global__ __launch_bounds__(256) void k_gather(const int* __restrict__ tokens,
                                                const float* __restrict__ emb,
                                                __hip_bfloat16* __restrict__ out) {
  const int t = blockIdx.x * 256 + threadIdx.x;
  const int e0 = t * 8;
  const int row = e0 >> 9;
  const int k = e0 & 511;
  const int tok = tokens[row];
  const float4* p = (const float4*)(emb + (size_t)tok * E_DIM + k);
  const float4 v0 = p[0], v1 = p[1];
  __align__(16) __hip_bfloat16 tmp[8];
  tmp[0] = __float2bfloat16(v0.x); tmp[1] = __float2bfloat16(v0.y);
  tmp[2] = __float2bfloat16(v0.z); tmp[3] = __float2bfloat16(v0.w);
  tmp[4] = __float2bfloat16(v1.x); tmp[5] = __float2bfloat16(v1.y);
  tmp[6] = __float2bfloat16(v1.z); tmp[7] = __float2bfloat16(v1.w);
  *(bf16x8*)(out + (size_t)t * 8) = *(const bf16x8*)tmp;
}

// ---------------- fp32 -> bf16 transpose (LDS tiled): dst[c*Rs+r]=src[r*Cs+c] ----------------
__global__ __launch_bounds__(256) void k_transpose_cast(const float* __restrict__ src,
                                                        __hip_bfloat16* __restrict__ dst,
                                                        int Rs, int Cs) {
  __shared__ float tile[32][33];
  const int tx = threadIdx.x & 31, ty = threadIdx.x >> 5;
  const int c0 = blockIdx.x * 32, r0 = blockIdx.y * 32;
  #pragma unroll
  for (int i = ty; i < 32; i += 8)
    tile[i][tx] = src[(size_t)(r0 + i) * Cs + c0 + tx];
  __syncthreads();
  #pragma unroll
  for (int i = ty; i < 32; i += 8)
    dst[(size_t)(c0 + i) * Rs + r0 + tx] = __float2bfloat16(tile[tx][i]);
}

// ---------------- combined bias for one direction: bi + bh ----------------
__global__ __launch_bounds__(256) void k_bias(const float* __restrict__ bi,
                                              const float* __restrict__ bh,
                                              float* __restrict__ bias) {
  const int n = blockIdx.x * 256 + threadIdx.x;
  bias[n] = bi[n] + bh[n];
}

// ---------------- chunk GEMM: Xc[8192,3072] = EmbChunk[8192,512] @ WiT^T + bias ----------------
__global__ __launch_bounds__(256) void k_gemm_x(const __hip_bfloat16* __restrict__ A,
                                                const __hip_bfloat16* __restrict__ BT,
                                                const float* __restrict__ bias,
                                                __hip_bfloat16* __restrict__ C) {
  __shared__ __align__(16) __hip_bfloat16 As[128][40];
  __shared__ __align__(16) __hip_bfloat16 Bs[128][40];
  const int tid = threadIdx.x;
  const int wave = tid >> 6, lane = tid & 63;
  const int q = lane >> 4, lr = lane & 15;
  const int wm = (wave >> 1) * 64, wn = (wave & 1) * 64;
  const int m0 = blockIdx.y * 128, n0 = blockIdx.x * 128;
  const int srow = tid >> 2, skseg = (tid & 3) * 8;

  f32x4 acc[4][4];
  #pragma unroll
  for (int i = 0; i < 4; ++i)
    #pragma unroll
    for (int j = 0; j < 4; ++j) { f32x4 z = {0.f, 0.f, 0.f, 0.f}; acc[i][j] = z; }

  for (int kt = 0; kt < 16; ++kt) {
    __syncthreads();
    const int kbase = kt * 32 + skseg;
    *(bf16x8*)&As[srow][skseg]      = *(const bf16x8*)(A + (size_t)(m0 + srow) * E_DIM + kbase);
    *(bf16x8*)&As[srow + 64][skseg] = *(const bf16x8*)(A + (size_t)(m0 + srow + 64) * E_DIM + kbase);
    *(bf16x8*)&Bs[srow][skseg]      = *(const bf16x8*)(BT + (size_t)(n0 + srow) * E_DIM + kbase);
    *(bf16x8*)&Bs[srow + 64][skseg] = *(const bf16x8*)(BT + (size_t)(n0 + srow + 64) * E_DIM + kbase);
    __syncthreads();
    bf16x8 af[4], bfr[4];
    #pragma unroll
    for (int mt = 0; mt < 4; ++mt) af[mt] = *(const bf16x8*)&As[wm + mt * 16 + lr][q * 8];
    #pragma unroll
    for (int nt = 0; nt < 4; ++nt) bfr[nt] = *(const bf16x8*)&Bs[wn + nt * 16 + lr][q * 8];
    #pragma unroll
    for (int mt = 0; mt < 4; ++mt)
      #pragma unroll
      for (int nt = 0; nt < 4; ++nt)
        acc[mt][nt] = __builtin_amdgcn_mfma_f32_16x16x32_bf16(af[mt], bfr[nt], acc[mt][nt], 0, 0, 0);
  }
  #pragma unroll
  for (int mt = 0; mt < 4; ++mt) {
    #pragma unroll
    for (int nt = 0; nt < 4; ++nt) {
      const int col = n0 + wn + nt * 16 + lr;
      const float bv = bias[col];
      #pragma unroll
      for (int i = 0; i < 4; ++i) {
        const int row = m0 + wm + mt * 16 + q * 4 + i;
        C[(size_t)row * G4 + col] = __float2bfloat16(acc[mt][nt][i] + bv);
      }
    }
  }
}

// ---------------- forward LSTM scan (one chunk of 128 steps) ----------------
// 48 persistent WGs = 4 batch groups (16 rows) x 12 col-slices (64 h-cols).
// h exchanged via relaxed agent-scope atomics (L2-bypassing; no cache-invalidating
// fences -> X/weights stay L2-hot). Flag-array barrier: per-WG arrival slots
// (128B-spaced stores, zero RMW contention), master aggregates via 11 parallel
// lane-polls, single release word. c-state in registers. X prefetched at step top.
__global__ __launch_bounds__(256, 1) void k_fwd_scan(const __hip_bfloat16* __restrict__ X,    // [8192,3072] chunk
                                                     const __hip_bfloat16* __restrict__ WhTf, // [3072,768]
                                                     __hip_bfloat16* __restrict__ hbuf,       // [2][64][768]
                                                     __hip_bfloat16* __restrict__ Hs,         // [32768,1536]
                                                     float* __restrict__ cstate,              // [64,768]
                                                     float* __restrict__ hT,                  // [64,768]
                                                     int* __restrict__ bar,                   // [4][16][32] ints
                                                     int chunk) {
  const int bx = blockIdx.x;
  const int group = bx / NSLICE;       // batch rows [16g, 16g+16)
  const int slice = bx % NSLICE;       // h cols [64*slice, 64*slice+64)
  const int r0 = group * 16;
  const int j0 = slice * 64;
  const int tid = threadIdx.x;
  const int w = tid >> 6;              // wave = gate index (r,f,g,o)
  const int lane = tid & 63;
  const int q = lane >> 4, lr = lane & 15;
  const int base = chunk * CHUNK;

  __shared__ __align__(16) __hip_bfloat16 h_stage[16][776];  // row pad: 768->776
  __shared__ float g_lds[4][16][65];

  const int brow = tid >> 4;           // 0..15 (batch row within group)
  const int c0 = (tid & 15) * 4;       // col quad within slice (0..60)

  // persistent c in registers (thread owns (brow, c0..c0+3) all steps)
  float4 creg = *(const float4*)(cstate + (size_t)(r0 + brow) * H_DIM + j0 + c0);

  int* grp = bar + group * 512;        // arrival slots: grp[slice*32]; release: grp[15*32]
  volatile int* rel = grp + 15 * 32;

  const int srow = tid >> 4, sc = tid & 15;
  const __hip_bfloat16* wbase = WhTf + (size_t)w * H_DIM * H_DIM;  // gate w's rows

  for (int s = 0; s < CHUNK; ++s) {
    const int gs = base + s;
    const __hip_bfloat16* hcur = hbuf + (size_t)(gs & 1) * (B_DIM * H_DIM);
    __hip_bfloat16* hnxt = hbuf + (size_t)((gs + 1) & 1) * (B_DIM * H_DIM);

    // ---- X prefetch for this step (independent of h; overlaps staging) ----
    uint2 xg[4];
    {
      const __hip_bfloat16* xp = X + ((size_t)s * B_DIM + r0 + brow) * G4 + j0 + c0;
      #pragma unroll
      for (int g = 0; g < 4; ++g) xg[g] = *(const uint2*)(xp + g * H_DIM);
    }

    // ---- stage this group's 16 h rows into LDS (L2-bypassing 8B loads) ----
    // row = 768 bf16 = 192 qwords; 16 lanes/row -> 12 iters
    {
      const ull_t* src = (const ull_t*)(hcur + (size_t)(r0 + srow) * H_DIM);
      ull_t* dst = (ull_t*)&h_stage[srow][0];
      #pragma unroll
      for (int it = 0; it < 12; ++it) {
        const int c8 = it * 16 + sc;
        dst[c8] = __hip_atomic_load(src + c8, __ATOMIC_RELAXED, __HIP_MEMORY_SCOPE_AGENT);
      }
    }
    __syncthreads();

    // ---- hidden GEMM for gate w: [16,768] x [768,64] -> 4 N-tiles ----
    f32x4 acc[4];
    #pragma unroll
    for (int nt = 0; nt < 4; ++nt) { f32x4 z = {0.f, 0.f, 0.f, 0.f}; acc[nt] = z; }
    #pragma unroll
    for (int kt = 0; kt < 24; ++kt) {
      const bf16x8 a = *(const bf16x8*)&h_stage[lr][kt * 32 + q * 8];
      const __hip_bfloat16* bp = wbase + (size_t)(j0 + lr) * H_DIM + kt * 32 + q * 8;
      #pragma unroll
      for (int nt = 0; nt < 4; ++nt) {
        const bf16x8 b = *(const bf16x8*)(bp + (size_t)nt * 16 * H_DIM);
        acc[nt] = __builtin_amdgcn_mfma_f32_16x16x32_bf16(a, b, acc[nt], 0, 0, 0);
      }
    }
    #pragma unroll
    for (int nt = 0; nt < 4; ++nt)
      #pragma unroll
      for (int i = 0; i < 4; ++i)
        g_lds[w][q * 4 + i][nt * 16 + lr] = acc[nt][i];
    __syncthreads();

    // ---- nonlinearity + c/h update: each thread owns (brow, c0..c0+3) ----
    {
      float rr[4], ff[4], gg[4], oo[4];
      #pragma unroll
      for (int i = 0; i < 4; ++i) {
        rr[i] = g_lds[0][brow][c0 + i];
        ff[i] = g_lds[1][brow][c0 + i];
        gg[i] = g_lds[2][brow][c0 + i];
        oo[i] = g_lds[3][brow][c0 + i];
      }
      rr[0] += bf_lo(xg[0].x); rr[1] += bf_hi(xg[0].x); rr[2] += bf_lo(xg[0].y); rr[3] += bf_hi(xg[0].y);
      ff[0] += bf_lo(xg[1].x); ff[1] += bf_hi(xg[1].x); ff[2] += bf_lo(xg[1].y); ff[3] += bf_hi(xg[1].y);
      gg[0] += bf_lo(xg[2].x); gg[1] += bf_hi(xg[2].x); gg[2] += bf_lo(xg[2].y); gg[3] += bf_hi(xg[2].y);
      oo[0] += bf_lo(xg[3].x); oo[1] += bf_hi(xg[3].x); oo[2] += bf_lo(xg[3].y); oo[3] += bf_hi(xg[3].y);
      float h[4];
      float* cr = &creg.x;
      #pragma unroll
      for (int i = 0; i < 4; ++i) {
        const float c = sigmf_(ff[i]) * cr[i] + sigmf_(rr[i]) * tanhf2(gg[i]);
        cr[i] = c;
        h[i] = sigmf_(oo[i]) * tanhf2(c);
      }
      const unsigned int p0 = packbf2(h[0], h[1]);
      const unsigned int p1 = packbf2(h[2], h[3]);
      const ull_t pv = ((ull_t)p1 << 32) | p0;
      __hip_atomic_store((ull_t*)(hnxt + (size_t)(r0 + brow) * H_DIM + j0 + c0), pv,
                         __ATOMIC_RELAXED, __HIP_MEMORY_SCOPE_AGENT);
      *(ull_t*)(Hs + ((size_t)gs * B_DIM + r0 + brow) * H2 + j0 + c0) = pv;
      if (chunk == 3 && s == CHUNK - 1) {
        float* hp = hT + (size_t)(r0 + brow) * H_DIM + j0 + c0;
        #pragma unroll
        for (int i = 0; i < 4; ++i) hp[i] = h[i];
      }
    }

    // ---- flag-array barrier (syncthreads drains vmcnt -> h stores visible) ----
    __syncthreads();
    const int gstep = gs + 1;
    if (slice == 0) {
      if (w == 0) {   // wave 0 of master WG: lanes 1..11 poll peer slots in parallel
        long guard = 0;
        for (;;) {
          int v = gstep;
          if (lane >= 1 && lane < NSLICE)
            v = __hip_atomic_load(&grp[lane * 32], __ATOMIC_RELAXED, __HIP_MEMORY_SCOPE_AGENT);
          if (__all(v >= gstep)) break;
          if (++guard > 64) __builtin_amdgcn_s_sleep(1);
          if (guard > (1L << 21)) break;   // fail visibly, never hang
        }
        if (lane == 0)
          __hip_atomic_store((int*)rel, gstep, __ATOMIC_RELEASE, __HIP_MEMORY_SCOPE_AGENT);
      }
    } else {
      if (tid == 0) {
        __hip_atomic_store(&grp[slice * 32], gstep, __ATOMIC_RELEASE, __HIP_MEMORY_SCOPE_AGENT);
        long guard = 0;
        while (__hip_atomic_load((int*)rel, __ATOMIC_RELAXED, __HIP_MEMORY_SCOPE_AGENT) < gstep) {
          if (++guard > 64) __builtin_amdgcn_s_sleep(1);
          if (guard > (1L << 21)) break;   // fail visibly, never hang
        }
      }
    }
    __syncthreads();
  }

  // persist c for next chunk
  *(float4*)(cstate + (size_t)(r0 + brow) * H_DIM + j0 + c0) = creg;
}

// ---------------- hTW[b,n] = hT[b,:] @ Wh_b[:,n] ----------------
__global__ __launch_bounds__(256) void k_hTW(const float* __restrict__ hT,
                                             const float* __restrict__ Whb,
                                             float* __restrict__ hTW) {
  const int b = blockIdx.y;
  const int n = blockIdx.x * 256 + threadIdx.x;
  __shared__ float hs[768];
  for (int i = threadIdx.x; i < 768; i += 256) hs[i] = hT[b * 768 + i];
  __syncthreads();
  float acc = 0.f;
  #pragma unroll 4
  for (int k = 0; k < 768; ++k) acc += hs[k] * Whb[(size_t)k * G4 + n];
  hTW[(size_t)b * G4 + n] = acc;
}

// ---------------- backward scan (one chunk, reverse): independent chains ----------------
__global__ __launch_bounds__(256) void k_bwd_scan(const __hip_bfloat16* __restrict__ X,
                                                  const float* __restrict__ hTW,
                                                  __hip_bfloat16* __restrict__ Hs,
                                                  float* __restrict__ c2state,
                                                  int chunk) {
  const int t = blockIdx.x * 256 + threadIdx.x;    // 49152
  const int b = t / H_DIM;
  const int j = t % H_DIM;
  const int base = chunk * CHUNK;
  const float hw0 = hTW[(size_t)b * G4 + j];
  const float hw1 = hTW[(size_t)b * G4 + 768 + j];
  const float hw2 = hTW[(size_t)b * G4 + 1536 + j];
  const float hw3 = hTW[(size_t)b * G4 + 2304 + j];
  float c2 = c2state[t];
  for (int s = CHUNK - 1; s >= 0; --s) {
    const size_t xb = ((size_t)s * B_DIM + b) * G4 + j;
    const float r = sigmf_(__bfloat162float(X[xb]) + hw0);
    const float f = sigmf_(__bfloat162float(X[xb + 768]) + hw1);
    const float g = tanhf2(__bfloat162float(X[xb + 1536]) + hw2);
    const float o = sigmf_(__bfloat162float(X[xb + 2304]) + hw3);
    c2 = f * c2 + r * g;
    Hs[((size_t)(base + s) * B_DIM + b) * H2 + H_DIM + j] = __float2bfloat16(o * tanhf2(c2));
  }
  c2state[t] = c2;
}

// ---------------- output: out[i,l] = Hs[i,:] @ Wout + bout (+pad bias) ----------------
__global__ __launch_bounds__(256) void k_out(const __hip_bfloat16* __restrict__ Hs,
                                             const float* __restrict__ Wout,
                                             const float* __restrict__ bout,
                                             const int* __restrict__ tokens,
                                             float* __restrict__ out) {
  __shared__ float rowbuf[8][1536];
  const int r0 = blockIdx.x * 8;
  const int tid = threadIdx.x;
  for (int idx = tid; idx < 8 * 1536; idx += 256) {
    const int rr = idx / 1536, k = idx % 1536;
    rowbuf[rr][k] = __bfloat162float(Hs[(size_t)(r0 + rr) * H2 + k]);
  }
  __syncthreads();
  const int l = tid & 31, rr = tid >> 5;
  float acc = bout[l];
  #pragma unroll 8
  for (int k = 0; k < 1536; ++k) acc += rowbuf[rr][k] * Wout[k * 32 + l];
  const int row = r0 + rr;
  if (l == 0 && tokens[row] == 1) acc += 10000.0f;
  out[(size_t)row * 32 + l] = acc;
}

// ---------------- host launcher ----------------
extern "C" void kernel_launch(void* const* d_in, const int* in_sizes, int n_in,
                              void* d_out, int out_size, void* d_ws, size_t ws_size,
                              hipStream_t stream) {
  const int*   tokens = (const int*)d_in[0];
  const float* emb    = (const float*)d_in[2];
  const float* Wi_f   = (const float*)d_in[3];
  const float* bi_f   = (const float*)d_in[4];
  const float* Wh_f   = (const float*)d_in[5];
  const float* bh_f   = (const float*)d_in[6];
  const float* Wi_b   = (const float*)d_in[7];
  const float* bi_b   = (const float*)d_in[8];
  const float* Wh_b   = (const float*)d_in[9];
  const float* bh_b   = (const float*)d_in[10];
  const float* Wout   = (const float*)d_in[11];
  const float* bout   = (const float*)d_in[12];
  float* out = (float*)d_out;
  char* ws = (char*)d_ws;

  size_t off = 0;
  auto alloc = [&](size_t bytes) { size_t o = off; off += (bytes + 255) & ~(size_t)255; return o; };
  const size_t oHs   = alloc((size_t)M_ROWS * H2 * 2);        // 100.7 MB
  const size_t oX    = alloc((size_t)CM * G4 * 2);            // 50.3 MB
  const size_t oEmb  = alloc((size_t)M_ROWS * E_DIM * 2);     // 33.6 MB
  const size_t oWiT  = alloc((size_t)G4 * E_DIM * 2);         // 3.1 MB
  const size_t oWhTf = alloc((size_t)G4 * H_DIM * 2);         // 4.7 MB
  const size_t oBias = alloc((size_t)G4 * 4);
  const size_t oHbuf = alloc((size_t)2 * B_DIM * H_DIM * 2);
  const size_t oCst  = alloc((size_t)B_DIM * H_DIM * 4);
  const size_t oHT   = alloc((size_t)B_DIM * H_DIM * 4);
  const size_t oHTW  = alloc((size_t)B_DIM * G4 * 4);
  const size_t oC2   = alloc((size_t)B_DIM * H_DIM * 4);
  const size_t oBar  = alloc(4 * 16 * 32 * 4);                // 8 KB flag array
  (void)ws_size; (void)in_sizes; (void)n_in; (void)out_size;   // total ~194 MB

  __hip_bfloat16* Hs   = (__hip_bfloat16*)(ws + oHs);
  __hip_bfloat16* X    = (__hip_bfloat16*)(ws + oX);
  __hip_bfloat16* Emb  = (__hip_bfloat16*)(ws + oEmb);
  __hip_bfloat16* WiT  = (__hip_bfloat16*)(ws + oWiT);
  __hip_bfloat16* WhTf = (__hip_bfloat16*)(ws + oWhTf);
  float*          Bias = (float*)(ws + oBias);
  __hip_bfloat16* Hbuf = (__hip_bfloat16*)(ws + oHbuf);
  float*          Cst  = (float*)(ws + oCst);
  float*          HT   = (float*)(ws + oHT);
  float*          HTW  = (float*)(ws + oHTW);
  float*          C2   = (float*)(ws + oC2);
  int*            Bar  = (int*)(ws + oBar);

  hipMemsetAsync(ws + oHbuf, 0, (size_t)2 * B_DIM * H_DIM * 2, stream);
  hipMemsetAsync(ws + oCst, 0, (size_t)B_DIM * H_DIM * 4, stream);
  hipMemsetAsync(ws + oC2, 0, (size_t)B_DIM * H_DIM * 4, stream);
  hipMemsetAsync(ws + oBar, 0, 4 * 16 * 32 * 4, stream);

  k_gather<<<8192, 256, 0, stream>>>(tokens, emb, Emb);
  k_transpose_cast<<<dim3(96, 24), 256, 0, stream>>>(Wh_f, WhTf, 768, 3072);

  // ---- forward direction: 4 chunks of (GEMM -> scan) ----
  k_transpose_cast<<<dim3(96, 16), 256, 0, stream>>>(Wi_f, WiT, 512, 3072);
  k_bias<<<12, 256, 0, stream>>>(bi_f, bh_f, Bias);
  for (int c = 0; c < 4; ++c) {
    k_gemm_x<<<dim3(24, 64), 256, 0, stream>>>(Emb + (size_t)c * CM * E_DIM, WiT, Bias, X);
    k_fwd_scan<<<48, 256, 0, stream>>>(X, WhTf, Hbuf, Hs, Cst, HT, Bar, c);
  }

  // ---- backward direction: hT@Wh_b once, then 4 chunks in reverse ----
  k_hTW<<<dim3(12, 64), 256, 0, stream>>>(HT, Wh_b, HTW);
  k_transpose_cast<<<dim3(96, 16), 256, 0, stream>>>(Wi_b, WiT, 512, 3072);
  k_bias<<<12, 256, 0, stream>>>(bi_b, bh_b, Bias);
  for (int c = 3; c >= 0; --c) {
    k_gemm_x<<<dim3(24, 64), 256, 0, stream>>>(Emb + (size_t)c * CM * E_DIM, WiT, Bias, X);
    k_bwd_scan<<<192, 256, 0, stream>>>(X, HTW, Hs, C2, c);
  }

  k_out<<<4096, 256, 0, stream>>>(Hs, Wout, bout, tokens, out);
}

// Round 6
// 4001.334 us; speedup vs baseline: 3.1408x; 1.4353x over previous
//
#include <hip/hip_runtime.h>
#include <hip/hip_bf16.h>
#include <stdint.h>

typedef __attribute__((ext_vector_type(8))) short bf16x8;
typedef __attribute__((ext_vector_type(4))) float f32x4;
typedef unsigned long long ull_t;

#define S_LEN 512
#define B_DIM 64
#define E_DIM 512
#define H_DIM 768
#define G4    3072      // 4H (one direction's gate width)
#define H2    1536      // 2H (combined hs row)
#define M_ROWS 32768    // S*B
#define CHUNK 128       // seq steps per X-chunk
#define CM    8192      // CHUNK*B rows per chunk
#define NGRP  4         // batch groups (16 rows each)
#define NSL   16        // col slices per group (48 cols = 16 words each)
#define WPR   256       // packed words per h row (256*3 = 768 cols)

__device__ __forceinline__ float sigmf_(float x) { return 1.0f / (1.0f + __expf(-x)); }
__device__ __forceinline__ float tanhf2(float x) {
  x = fminf(fmaxf(x, -20.0f), 20.0f);
  float e = __expf(2.0f * x);
  return (e - 1.0f) / (e + 1.0f);
}
__device__ __forceinline__ float bfu(unsigned short u) { return __uint_as_float((unsigned)u << 16); }
__device__ __forceinline__ unsigned short packbf(float a) {
  __hip_bfloat16 t = __float2bfloat16(a);
  unsigned short b;
  __builtin_memcpy(&b, &t, 2);
  return b;
}

// ---------------- embedding gather + cast to bf16 ----------------
__global__ __launch_bounds__(256) void k_gather(const int* __restrict__ tokens,
                                                const float* __restrict__ emb,
                                                __hip_bfloat16* __restrict__ out) {
  const int t = blockIdx.x * 256 + threadIdx.x;
  const int e0 = t * 8;
  const int row = e0 >> 9;
  const int k = e0 & 511;
  const int tok = tokens[row];
  const float4* p = (const float4*)(emb + (size_t)tok * E_DIM + k);
  const float4 v0 = p[0], v1 = p[1];
  __align__(16) __hip_bfloat16 tmp[8];
  tmp[0] = __float2bfloat16(v0.x); tmp[1] = __float2bfloat16(v0.y);
  tmp[2] = __float2bfloat16(v0.z); tmp[3] = __float2bfloat16(v0.w);
  tmp[4] = __float2bfloat16(v1.x); tmp[5] = __float2bfloat16(v1.y);
  tmp[6] = __float2bfloat16(v1.z); tmp[7] = __float2bfloat16(v1.w);
  *(bf16x8*)(out + (size_t)t * 8) = *(const bf16x8*)tmp;
}

// ---------------- fp32 -> bf16 transpose (LDS tiled): dst[c*Rs+r]=src[r*Cs+c] ----------------
__global__ __launch_bounds__(256) void k_transpose_cast(const float* __restrict__ src,
                                                        __hip_bfloat16* __restrict__ dst,
                                                        int Rs, int Cs) {
  __shared__ float tile[32][33];
  const int tx = threadIdx.x & 31, ty = threadIdx.x >> 5;
  const int c0 = blockIdx.x * 32, r0 = blockIdx.y * 32;
  #pragma unroll
  for (int i = ty; i < 32; i += 8)
    tile[i][tx] = src[(size_t)(r0 + i) * Cs + c0 + tx];
  __syncthreads();
  #pragma unroll
  for (int i = ty; i < 32; i += 8)
    dst[(size_t)(c0 + i) * Rs + r0 + tx] = __float2bfloat16(tile[tx][i]);
}

// ---------------- combined bias for one direction: bi + bh ----------------
__global__ __launch_bounds__(256) void k_bias(const float* __restrict__ bi,
                                              const float* __restrict__ bh,
                                              float* __restrict__ bias) {
  const int n = blockIdx.x * 256 + threadIdx.x;
  bias[n] = bi[n] + bh[n];
}

// ---------------- chunk GEMM: Xc[8192,3072] = EmbChunk[8192,512] @ WiT^T + bias ----------------
__global__ __launch_bounds__(256) void k_gemm_x(const __hip_bfloat16* __restrict__ A,
                                                const __hip_bfloat16* __restrict__ BT,
                                                const float* __restrict__ bias,
                                                __hip_bfloat16* __restrict__ C) {
  __shared__ __align__(16) __hip_bfloat16 As[128][40];
  __shared__ __align__(16) __hip_bfloat16 Bs[128][40];
  const int tid = threadIdx.x;
  const int wave = tid >> 6, lane = tid & 63;
  const int q = lane >> 4, lr = lane & 15;
  const int wm = (wave >> 1) * 64, wn = (wave & 1) * 64;
  const int m0 = blockIdx.y * 128, n0 = blockIdx.x * 128;
  const int srow = tid >> 2, skseg = (tid & 3) * 8;

  f32x4 acc[4][4];
  #pragma unroll
  for (int i = 0; i < 4; ++i)
    #pragma unroll
    for (int j = 0; j < 4; ++j) { f32x4 z = {0.f, 0.f, 0.f, 0.f}; acc[i][j] = z; }

  for (int kt = 0; kt < 16; ++kt) {
    __syncthreads();
    const int kbase = kt * 32 + skseg;
    *(bf16x8*)&As[srow][skseg]      = *(const bf16x8*)(A + (size_t)(m0 + srow) * E_DIM + kbase);
    *(bf16x8*)&As[srow + 64][skseg] = *(const bf16x8*)(A + (size_t)(m0 + srow + 64) * E_DIM + kbase);
    *(bf16x8*)&Bs[srow][skseg]      = *(const bf16x8*)(BT + (size_t)(n0 + srow) * E_DIM + kbase);
    *(bf16x8*)&Bs[srow + 64][skseg] = *(const bf16x8*)(BT + (size_t)(n0 + srow + 64) * E_DIM + kbase);
    __syncthreads();
    bf16x8 af[4], bfr[4];
    #pragma unroll
    for (int mt = 0; mt < 4; ++mt) af[mt] = *(const bf16x8*)&As[wm + mt * 16 + lr][q * 8];
    #pragma unroll
    for (int nt = 0; nt < 4; ++nt) bfr[nt] = *(const bf16x8*)&Bs[wn + nt * 16 + lr][q * 8];
    #pragma unroll
    for (int mt = 0; mt < 4; ++mt)
      #pragma unroll
      for (int nt = 0; nt < 4; ++nt)
        acc[mt][nt] = __builtin_amdgcn_mfma_f32_16x16x32_bf16(af[mt], bfr[nt], acc[mt][nt], 0, 0, 0);
  }
  #pragma unroll
  for (int mt = 0; mt < 4; ++mt) {
    #pragma unroll
    for (int nt = 0; nt < 4; ++nt) {
      const int col = n0 + wn + nt * 16 + lr;
      const float bv = bias[col];
      #pragma unroll
      for (int i = 0; i < 4; ++i) {
        const int row = m0 + wm + mt * 16 + q * 4 + i;
        C[(size_t)row * G4 + col] = __float2bfloat16(acc[mt][nt][i] + bv);
      }
    }
  }
}

// ---------------- forward LSTM scan: BARRIER-FREE tag-in-data systolic ----------------
// 64 WGs = 4 batch groups (16 rows) x 16 col-slices (48 cols = 16 packed words).
// h exchanged as 8B words [tag16 | 3 x bf16] via relaxed agent atomics. Consumers
// poll the data words until tag == step: ONE IC round trip replaces the 5-hop
// flag barrier. Double-buffer safety proven by phase order (stage -> produce).
__global__ __launch_bounds__(256, 1) void k_fwd_scan(const __hip_bfloat16* __restrict__ X,    // [8192,3072] chunk
                                                     const __hip_bfloat16* __restrict__ WhTf, // [3072,768]
                                                     ull_t* __restrict__ hbuf,                // [2][64][256] packed
                                                     __hip_bfloat16* __restrict__ Hs,         // [32768,1536]
                                                     float* __restrict__ cstate,              // [64,768]
                                                     float* __restrict__ hT,                  // [64,768]
                                                     int chunk) {
  const int bx = blockIdx.x;
  const int group = bx >> 4;           // batch rows [16g, 16g+16)
  const int slice = bx & 15;           // cols [48*slice, 48*slice+48)
  const int r0 = group * 16;
  const int j0 = slice * 48;
  const int w0 = slice * 16;           // word offset within row
  const int tid = threadIdx.x;
  const int w = tid >> 6;              // wave = gate index (r,f,g,o)
  const int lane = tid & 63;
  const int q = lane >> 4, lr = lane & 15;
  const int base = chunk * CHUNK;

  const int row = tid >> 4;            // 0..15: batch row within group
  const int wloc = tid & 15;           // 0..15: this thread's word lane
  const int col0 = 3 * wloc;           // 0..45: first owned col within slice

  __shared__ unsigned short h_stage[16][776];   // unpacked bf16 bits, padded row
  __shared__ float g_lds[4][16][50];

  // persistent c in registers: thread owns (row, col0..col0+2)
  float cr[3];
  {
    const float* cs = cstate + (size_t)(r0 + row) * H_DIM + j0 + col0;
    cr[0] = cs[0]; cr[1] = cs[1]; cr[2] = cs[2];
  }

  const __hip_bfloat16* wbase = WhTf + (size_t)w * H_DIM * H_DIM;  // gate w's rows

  for (int s = 0; s < CHUNK; ++s) {
    const int gs = base + s;

    // ---- X loads for this step (independent of h; overlap the poll) ----
    unsigned short xs[4][3];
    {
      const unsigned short* xp = (const unsigned short*)(X + ((size_t)s * B_DIM + r0 + row) * G4 + j0 + col0);
      #pragma unroll
      for (int g = 0; g < 4; ++g)
        #pragma unroll
        for (int j = 0; j < 3; ++j) xs[g][j] = xp[g * H_DIM + j];
    }

    // ---- poll + stage h_gs: 16 words/thread across this row ----
    {
      const ull_t* hc = hbuf + ((size_t)(gs & 1) << 14) + (size_t)(r0 + row) * WPR + wloc;
      ull_t v[16];
      const unsigned short expct = (unsigned short)gs;
      unsigned need = 0xFFFFu;
      long guard = 0;
      for (;;) {
        #pragma unroll
        for (int i = 0; i < 16; ++i)
          if (need & (1u << i))
            v[i] = __hip_atomic_load(hc + 16 * i, __ATOMIC_RELAXED, __HIP_MEMORY_SCOPE_AGENT);
        unsigned nn = 0;
        #pragma unroll
        for (int i = 0; i < 16; ++i)
          if ((need & (1u << i)) && ((unsigned short)v[i] != expct)) nn |= 1u << i;
        need = nn;
        if (!need) break;
        if (++guard > (1L << 22)) break;   // fail visibly, never hang
      }
      #pragma unroll
      for (int i = 0; i < 16; ++i) {
        const int cc = 3 * (wloc + 16 * i);
        const ull_t x = v[i];
        h_stage[row][cc]     = (unsigned short)(x >> 16);
        h_stage[row][cc + 1] = (unsigned short)(x >> 32);
        h_stage[row][cc + 2] = (unsigned short)(x >> 48);
      }
    }
    __syncthreads();

    // ---- hidden GEMM for gate w: [16,768] x [768,48] -> 3 N-tiles ----
    f32x4 acc[3];
    #pragma unroll
    for (int nt = 0; nt < 3; ++nt) { f32x4 z = {0.f, 0.f, 0.f, 0.f}; acc[nt] = z; }
    #pragma unroll
    for (int kt = 0; kt < 24; ++kt) {
      const bf16x8 a = *(const bf16x8*)&h_stage[lr][kt * 32 + q * 8];
      const __hip_bfloat16* bp = wbase + (size_t)(j0 + lr) * H_DIM + kt * 32 + q * 8;
      #pragma unroll
      for (int nt = 0; nt < 3; ++nt) {
        const bf16x8 b = *(const bf16x8*)(bp + (size_t)nt * 16 * H_DIM);
        acc[nt] = __builtin_amdgcn_mfma_f32_16x16x32_bf16(a, b, acc[nt], 0, 0, 0);
      }
    }
    #pragma unroll
    for (int nt = 0; nt < 3; ++nt)
      #pragma unroll
      for (int i = 0; i < 4; ++i)
        g_lds[w][q * 4 + i][nt * 16 + lr] = acc[nt][i];
    __syncthreads();

    // ---- nonlinearity + c/h update: thread owns (row, col0..col0+2) ----
    {
      float h[3];
      #pragma unroll
      for (int j = 0; j < 3; ++j) {
        const float rv = g_lds[0][row][col0 + j] + bfu(xs[0][j]);
        const float fv = g_lds[1][row][col0 + j] + bfu(xs[1][j]);
        const float gv = g_lds[2][row][col0 + j] + bfu(xs[2][j]);
        const float ov = g_lds[3][row][col0 + j] + bfu(xs[3][j]);
        const float c = sigmf_(fv) * cr[j] + sigmf_(rv) * tanhf2(gv);
        cr[j] = c;
        h[j] = sigmf_(ov) * tanhf2(c);
      }
      const unsigned short b0 = packbf(h[0]), b1 = packbf(h[1]), b2 = packbf(h[2]);
      const ull_t wv = (ull_t)(unsigned short)(gs + 1)
                     | ((ull_t)b0 << 16) | ((ull_t)b1 << 32) | ((ull_t)b2 << 48);
      __hip_atomic_store(hbuf + ((size_t)((gs + 1) & 1) << 14) + (size_t)(r0 + row) * WPR + w0 + wloc,
                         wv, __ATOMIC_RELAXED, __HIP_MEMORY_SCOPE_AGENT);
      unsigned short* hsp = (unsigned short*)(Hs + ((size_t)gs * B_DIM + r0 + row) * H2 + j0 + col0);
      hsp[0] = b0; hsp[1] = b1; hsp[2] = b2;
      if (chunk == 3 && s == CHUNK - 1) {
        float* hp = hT + (size_t)(r0 + row) * H_DIM + j0 + col0;
        hp[0] = h[0]; hp[1] = h[1]; hp[2] = h[2];
      }
    }
    // no barrier: next staging __syncthreads orders h_stage/g_lds reuse
  }

  // persist c for next chunk
  {
    float* cs = cstate + (size_t)(r0 + row) * H_DIM + j0 + col0;
    cs[0] = cr[0]; cs[1] = cr[1]; cs[2] = cr[2];
  }
}

// ---------------- hTW[b,n] = hT[b,:] @ Wh_b[:,n] ----------------
__global__ __launch_bounds__(256) void k_hTW(const float* __restrict__ hT,
                                             const float* __restrict__ Whb,
                                             float* __restrict__ hTW) {
  const int b = blockIdx.y;
  const int n = blockIdx.x * 256 + threadIdx.x;
  __shared__ float hs[768];
  for (int i = threadIdx.x; i < 768; i += 256) hs[i] = hT[b * 768 + i];
  __syncthreads();
  float acc = 0.f;
  #pragma unroll 4
  for (int k = 0; k < 768; ++k) acc += hs[k] * Whb[(size_t)k * G4 + n];
  hTW[(size_t)b * G4 + n] = acc;
}

// ---------------- backward scan (one chunk, reverse): independent chains ----------------
__global__ __launch_bounds__(256) void k_bwd_scan(const __hip_bfloat16* __restrict__ X,
                                                  const float* __restrict__ hTW,
                                                  __hip_bfloat16* __restrict__ Hs,
                                                  float* __restrict__ c2state,
                                                  int chunk) {
  const int t = blockIdx.x * 256 + threadIdx.x;    // 49152
  const int b = t / H_DIM;
  const int j = t % H_DIM;
  const int base = chunk * CHUNK;
  const float hw0 = hTW[(size_t)b * G4 + j];
  const float hw1 = hTW[(size_t)b * G4 + 768 + j];
  const float hw2 = hTW[(size_t)b * G4 + 1536 + j];
  const float hw3 = hTW[(size_t)b * G4 + 2304 + j];
  float c2 = c2state[t];
  for (int s = CHUNK - 1; s >= 0; --s) {
    const size_t xb = ((size_t)s * B_DIM + b) * G4 + j;
    const float r = sigmf_(__bfloat162float(X[xb]) + hw0);
    const float f = sigmf_(__bfloat162float(X[xb + 768]) + hw1);
    const float g = tanhf2(__bfloat162float(X[xb + 1536]) + hw2);
    const float o = sigmf_(__bfloat162float(X[xb + 2304]) + hw3);
    c2 = f * c2 + r * g;
    Hs[((size_t)(base + s) * B_DIM + b) * H2 + H_DIM + j] = __float2bfloat16(o * tanhf2(c2));
  }
  c2state[t] = c2;
}

// ---------------- output: out[i,l] = Hs[i,:] @ Wout + bout (+pad bias) ----------------
__global__ __launch_bounds__(256) void k_out(const __hip_bfloat16* __restrict__ Hs,
                                             const float* __restrict__ Wout,
                                             const float* __restrict__ bout,
                                             const int* __restrict__ tokens,
                                             float* __restrict__ out) {
  __shared__ float rowbuf[8][1536];
  const int r0 = blockIdx.x * 8;
  const int tid = threadIdx.x;
  for (int idx = tid; idx < 8 * 1536; idx += 256) {
    const int rr = idx / 1536, k = idx % 1536;
    rowbuf[rr][k] = __bfloat162float(Hs[(size_t)(r0 + rr) * H2 + k]);
  }
  __syncthreads();
  const int l = tid & 31, rr = tid >> 5;
  float acc = bout[l];
  #pragma unroll 8
  for (int k = 0; k < 1536; ++k) acc += rowbuf[rr][k] * Wout[k * 32 + l];
  const int row = r0 + rr;
  if (l == 0 && tokens[row] == 1) acc += 10000.0f;
  out[(size_t)row * 32 + l] = acc;
}

// ---------------- host launcher ----------------
extern "C" void kernel_launch(void* const* d_in, const int* in_sizes, int n_in,
                              void* d_out, int out_size, void* d_ws, size_t ws_size,
                              hipStream_t stream) {
  const int*   tokens = (const int*)d_in[0];
  const float* emb    = (const float*)d_in[2];
  const float* Wi_f   = (const float*)d_in[3];
  const float* bi_f   = (const float*)d_in[4];
  const float* Wh_f   = (const float*)d_in[5];
  const float* bh_f   = (const float*)d_in[6];
  const float* Wi_b   = (const float*)d_in[7];
  const float* bi_b   = (const float*)d_in[8];
  const float* Wh_b   = (const float*)d_in[9];
  const float* bh_b   = (const float*)d_in[10];
  const float* Wout   = (const float*)d_in[11];
  const float* bout   = (const float*)d_in[12];
  float* out = (float*)d_out;
  char* ws = (char*)d_ws;

  size_t off = 0;
  auto alloc = [&](size_t bytes) { size_t o = off; off += (bytes + 255) & ~(size_t)255; return o; };
  const size_t oHs   = alloc((size_t)M_ROWS * H2 * 2);        // 100.7 MB
  const size_t oX    = alloc((size_t)CM * G4 * 2);            // 50.3 MB
  const size_t oEmb  = alloc((size_t)M_ROWS * E_DIM * 2);     // 33.6 MB
  const size_t oWiT  = alloc((size_t)G4 * E_DIM * 2);         // 3.1 MB
  const size_t oWhTf = alloc((size_t)G4 * H_DIM * 2);         // 4.7 MB
  const size_t oBias = alloc((size_t)G4 * 4);
  const size_t oHbuf = alloc((size_t)2 * B_DIM * WPR * 8);    // 256 KB packed h
  const size_t oCst  = alloc((size_t)B_DIM * H_DIM * 4);
  const size_t oHT   = alloc((size_t)B_DIM * H_DIM * 4);
  const size_t oHTW  = alloc((size_t)B_DIM * G4 * 4);
  const size_t oC2   = alloc((size_t)B_DIM * H_DIM * 4);
  (void)ws_size; (void)in_sizes; (void)n_in; (void)out_size;   // total ~194 MB

  __hip_bfloat16* Hs   = (__hip_bfloat16*)(ws + oHs);
  __hip_bfloat16* X    = (__hip_bfloat16*)(ws + oX);
  __hip_bfloat16* Emb  = (__hip_bfloat16*)(ws + oEmb);
  __hip_bfloat16* WiT  = (__hip_bfloat16*)(ws + oWiT);
  __hip_bfloat16* WhTf = (__hip_bfloat16*)(ws + oWhTf);
  float*          Bias = (float*)(ws + oBias);
  ull_t*          Hbuf = (ull_t*)(ws + oHbuf);
  float*          Cst  = (float*)(ws + oCst);
  float*          HT   = (float*)(ws + oHT);
  float*          HTW  = (float*)(ws + oHTW);
  float*          C2   = (float*)(ws + oC2);

  hipMemsetAsync(ws + oHbuf, 0, (size_t)2 * B_DIM * WPR * 8, stream);  // h_0 = 0, tag 0
  hipMemsetAsync(ws + oCst, 0, (size_t)B_DIM * H_DIM * 4, stream);
  hipMemsetAsync(ws + oC2, 0, (size_t)B_DIM * H_DIM * 4, stream);

  k_gather<<<8192, 256, 0, stream>>>(tokens, emb, Emb);
  k_transpose_cast<<<dim3(96, 24), 256, 0, stream>>>(Wh_f, WhTf, 768, 3072);

  // ---- forward direction: 4 chunks of (GEMM -> scan) ----
  k_transpose_cast<<<dim3(96, 16), 256, 0, stream>>>(Wi_f, WiT, 512, 3072);
  k_bias<<<12, 256, 0, stream>>>(bi_f, bh_f, Bias);
  for (int c = 0; c < 4; ++c) {
    k_gemm_x<<<dim3(24, 64), 256, 0, stream>>>(Emb + (size_t)c * CM * E_DIM, WiT, Bias, X);
    k_fwd_scan<<<64, 256, 0, stream>>>(X, WhTf, Hbuf, Hs, Cst, HT, c);
  }

  // ---- backward direction: hT@Wh_b once, then 4 chunks in reverse ----
  k_hTW<<<dim3(12, 64), 256, 0, stream>>>(HT, Wh_b, HTW);
  k_transpose_cast<<<dim3(96, 16), 256, 0, stream>>>(Wi_b, WiT, 512, 3072);
  k_bias<<<12, 256, 0, stream>>>(bi_b, bh_b, Bias);
  for (int c = 3; c >= 0; --c) {
    k_gemm_x<<<dim3(24, 64), 256, 0, stream>>>(Emb + (size_t)c * CM * E_DIM, WiT, Bias, X);
    k_bwd_scan<<<192, 256, 0, stream>>>(X, HTW, Hs, C2, c);
  }

  k_out<<<4096, 256, 0, stream>>>(Hs, Wout, bout, tokens, out);
}